// Round 4
// baseline (128.209 us; speedup 1.0000x reference)
//
#include <hip/hip_runtime.h>

// ApproxNDCGLoss, N=20000, fp32 — ONE dispatch; coherent footprint = 64 floats.
//
// Round-3 post-mortem: kernel 82 us, FETCH 7.3 MB / WRITE 13.1 MB — same as
// round 2 even with zero fences => traffic was the ~240K per-element
// agent-scope atomic loads (prefix/ybkt rank lookups), each an uncacheable
// IF$ round-trip (they bypass XCD L2 by design). The bulk data never needed
// to be coherent: only the 64 Chebyshev node sums structurally cross the
// barrier.
//
// This version:
//  - Block 0: counting sort with ybkt[20480] + prefix IN LDS (97 KB static,
//    1 block/CU — fine, 65 blocks on 256 CUs), then idcg + ysum entirely
//    LDS-local (plain ds_read; ~236K LDS loads ~ 1 MB @ ~69 TB/s). Publishes
//    TWO f64 atomic adds. Generic-pointer fallback to block-private global
//    g_ybkt if n > 20480.
//  - Blocks 1..64: node F_k sums (unchanged, verified); publish 64 floats
//    via relaxed agent stores (IF$-coherent, no cache-maintenance ops).
//  - Barrier: unchanged from round 3 (vmcnt drain + relaxed arrive/spin —
//    proven correct, absmax 0.0).
//  - Phase 2: dcg-only barycentric over ~308-elem chunks on all 65 blocks;
//    3 f64 atomic adds per block; vmcnt-ordered ticket finalize; self-clean.

#define LOG2E 1.442695040888963387f
#define M_NODES 64
#define XHALF 8.0
#define NB 2048
#define PI_D 3.14159265358979323846
#define BT 1024
#define GBLKS (M_NODES + 1)
#define LDS_N 20480
#define MAXN 131072

#if __has_builtin(__builtin_amdgcn_exp2f)
#define EXP2(x) __builtin_amdgcn_exp2f(x)
#else
#define EXP2(x) exp2f(x)
#endif

#if __has_builtin(__builtin_amdgcn_rcpf)
#define RCP(x) __builtin_amdgcn_rcpf(x)
#else
#define RCP(x) (1.0f / (x))
#endif

#define WAIT_VM0() asm volatile("s_waitcnt vmcnt(0)" ::: "memory")

// ---- module-global state ----
__device__ double g_acc[3] = {0.0, 0.0, 0.0};  // dcg, idcg, ysum
__device__ int g_done = 0;
__device__ int g_bar = 0;
__device__ float g_nodef[M_NODES];  // the ONLY cross-block bulk data (256 B)
__device__ float g_ybkt[MAXN];      // block-0-PRIVATE fallback (n > LDS_N)

__device__ __forceinline__ int bucket_of(float y) {
  int b = (int)(y * (float)NB);
  return b < 0 ? 0 : (b > NB - 1 ? NB - 1 : b);
}

// relaxed agent-scope atomics: bypass XCD L2, coherent at IF$, NO cache ops
__device__ __forceinline__ float aloadf(const float* p) {
  return __hip_atomic_load(p, __ATOMIC_RELAXED, __HIP_MEMORY_SCOPE_AGENT);
}
__device__ __forceinline__ int aloadi(const int* p) {
  return __hip_atomic_load(p, __ATOMIC_RELAXED, __HIP_MEMORY_SCOPE_AGENT);
}
__device__ __forceinline__ double aloadd(const double* p) {
  return __hip_atomic_load(p, __ATOMIC_RELAXED, __HIP_MEMORY_SCOPE_AGENT);
}
__device__ __forceinline__ void astoref(float* p, float v) {
  __hip_atomic_store(p, v, __ATOMIC_RELAXED, __HIP_MEMORY_SCOPE_AGENT);
}
__device__ __forceinline__ void astorei(int* p, int v) {
  __hip_atomic_store(p, v, __ATOMIC_RELAXED, __HIP_MEMORY_SCOPE_AGENT);
}
__device__ __forceinline__ void astored(double* p, double v) {
  __hip_atomic_store(p, v, __ATOMIC_RELAXED, __HIP_MEMORY_SCOPE_AGENT);
}
__device__ __forceinline__ void aaddd(double* p, double v) {
  __hip_atomic_fetch_add(p, v, __ATOMIC_RELAXED, __HIP_MEMORY_SCOPE_AGENT);
}
__device__ __forceinline__ int afetchaddi(int* p, int v) {
  return __hip_atomic_fetch_add(p, v, __ATOMIC_RELAXED,
                                __HIP_MEMORY_SCOPE_AGENT);
}

__global__ __launch_bounds__(BT) void fused_kernel(
    const float* __restrict__ s, const float* __restrict__ y,
    float* __restrict__ out, int n) {
  const int tid = threadIdx.x;
  const int blk = blockIdx.x;
  const int lane = tid & 63;

  __shared__ int hist[NB];          // histogram, then scatter cursor (8 KB)
  __shared__ int sprefix[NB + 1];   // bucket starts, block 0 only (8.2 KB)
  __shared__ float ybkt_lds[LDS_N]; // sorted y, block 0 only (80 KB)
  __shared__ float2 nd[M_NODES];    // phase-2 node table
  __shared__ double wsum[48];       // block reduction scratch
  __shared__ int wrep[16];          // scan wave partials

  // ---------------- phase 1 ----------------
  if (blk == 0) {
    // --- counting sort of y + idcg + ysum: ALL block-local ---
    for (int b = tid; b < NB; b += BT) hist[b] = 0;
    __syncthreads();

    const float4* y4 = (const float4*)y;
    const int n4 = n >> 2;
    for (int i = tid; i < n4; i += BT) {
      const float4 v = y4[i];
      atomicAdd(&hist[bucket_of(v.x)], 1);
      atomicAdd(&hist[bucket_of(v.y)], 1);
      atomicAdd(&hist[bucket_of(v.z)], 1);
      atomicAdd(&hist[bucket_of(v.w)], 1);
    }
    for (int i = (n4 << 2) + tid; i < n; i += BT)
      atomicAdd(&hist[bucket_of(y[i])], 1);
    __syncthreads();

    // exclusive scan (2 bins/thread), shuffle-based, 2 barriers
    const int base = tid * 2;
    const int l0 = hist[base], l1 = hist[base + 1];
    const int sum2 = l0 + l1;
    int v = sum2;
#pragma unroll
    for (int d = 1; d < 64; d <<= 1) {
      const int t = __shfl_up(v, d);
      if (lane >= d) v += t;
    }
    if (lane == 63) wrep[tid >> 6] = v;
    __syncthreads();
    if (tid < 16) {
      int wv = wrep[tid];
#pragma unroll
      for (int d = 1; d < 16; d <<= 1) {
        const int t = __shfl_up(wv, d);
        if (tid >= d) wv += t;
      }
      wrep[tid] = wv;
    }
    __syncthreads();
    const int wbase = (tid >> 6) ? wrep[(tid >> 6) - 1] : 0;
    const int incl = wbase + v;
    const int run = incl - sum2;
    sprefix[base] = run;
    sprefix[base + 1] = run + l0;
    if (tid == BT - 1) sprefix[NB] = incl;  // == n
    hist[base] = run;  // scatter cursor
    hist[base + 1] = run + l0;
    __syncthreads();

    // scatter + rank-count, parameterized on ybkt storage (LDS fast path)
    double ic = 0.0, ys = 0.0;
    auto sort_body = [&](float* ybkt) {
      for (int i = tid; i < n4; i += BT) {
        const float4 v4 = y4[i];
        ybkt[atomicAdd(&hist[bucket_of(v4.x)], 1)] = v4.x;
        ybkt[atomicAdd(&hist[bucket_of(v4.y)], 1)] = v4.y;
        ybkt[atomicAdd(&hist[bucket_of(v4.z)], 1)] = v4.z;
        ybkt[atomicAdd(&hist[bucket_of(v4.w)], 1)] = v4.w;
      }
      for (int i = (n4 << 2) + tid; i < n; i += BT) {
        const float yv = y[i];
        ybkt[atomicAdd(&hist[bucket_of(yv)], 1)] = yv;
      }
      __syncthreads();  // scatter complete before same-block reads

      // idcg + ysum: exact rank via strict-greater count, block-local reads
      for (int i = tid; i < n; i += BT) {
        const float yv = y[i];
        const int b = bucket_of(yv);
        const int s0 = sprefix[b], s1 = sprefix[b + 1];
        int cnt = n - s1;  // strictly higher buckets
        for (int t = s0; t < s1; ++t) cnt += (ybkt[t] > yv);
        ic += (double)yv / log2((double)cnt + 2.0);
        ys += (double)yv;
      }
    };
    if (n <= LDS_N) sort_body(ybkt_lds);
    else sort_body(g_ybkt);  // block-private global fallback (plain ops)

    for (int off = 32; off > 0; off >>= 1) {
      ic += __shfl_down(ic, off);
      ys += __shfl_down(ys, off);
    }
    if (lane == 0) {
      wsum[tid >> 6] = ic;
      wsum[(tid >> 6) + 16] = ys;
    }
    __syncthreads();
    if (tid == 0) {
      double b = 0.0, c = 0.0;
#pragma unroll
      for (int w = 0; w < 16; ++w) {
        b += wsum[w];
        c += wsum[w + 16];
      }
      aaddd(&g_acc[1], b);  // relaxed f64 RMW at IF$
      aaddd(&g_acc[2], c);
    }
  } else {
    // --- node k: F(x_k) = sum_i sigmoid(x_k - s_i) (verified math) ---
    const int k = blk - 1;
    const float xk =
        (float)(XHALF * cos(PI_D * (double)k / (double)(M_NODES - 1)));
    double F = 0.0;
    const float4* s4 = (const float4*)s;
    const int n4 = n >> 2;
    for (int i = tid; i < n4; i += BT) {
      const float4 v = s4[i];
      float t = RCP(1.0f + EXP2((v.x - xk) * LOG2E));
      t += RCP(1.0f + EXP2((v.y - xk) * LOG2E));
      t += RCP(1.0f + EXP2((v.z - xk) * LOG2E));
      t += RCP(1.0f + EXP2((v.w - xk) * LOG2E));
      F += (double)t;
    }
    for (int i = (n4 << 2) + tid; i < n; i += BT)
      F += (double)RCP(1.0f + EXP2((s[i] - xk) * LOG2E));
    for (int off = 32; off > 0; off >>= 1) F += __shfl_down(F, off);
    if (lane == 0) wsum[tid >> 6] = F;
    __syncthreads();
    if (tid == 0) {
      double t = 0.0;
#pragma unroll
      for (int w = 0; w < 16; ++w) t += wsum[w];
      astoref(&g_nodef[k], (float)t);  // publish to IF$
    }
  }

  // -------- grid barrier: drain own stores, relaxed arrive+spin ----------
  WAIT_VM0();       // every wave: its IF$ stores/RMWs are complete
  __syncthreads();  // join all waves of this block
  if (tid == 0) {
    afetchaddi(&g_bar, 1);  // relaxed RMW at IF$ — no wbl2/inv
    while (aloadi(&g_bar) < GBLKS) __builtin_amdgcn_s_sleep(16);
  }
  __syncthreads();

  // ---------------- phase 2: dcg via barycentric F(s_j) ----------------
  if (tid < M_NODES) {
    const float xk =
        (float)(XHALF * cos(PI_D * (double)tid / (double)(M_NODES - 1)));
    nd[tid] = make_float2(xk, aloadf(&g_nodef[tid]));  // IF$ read — fresh
  }
  __syncthreads();

  const int chunk = (n + GBLKS - 1) / GBLKS;  // ~308
  const int j0 = blk * chunk;
  const int j1 = (j0 + chunk < n) ? (j0 + chunk) : n;
  double dc = 0.0;
  for (int j = j0 + tid; j < j1; j += BT) {
    const float x = s[j];
    const float yj = y[j];
    double num = 0.0, den = 0.0;
    int hit = -1;
#pragma unroll
    for (int k = 0; k < M_NODES; ++k) {
      const float d = x - nd[k].x;
      float w = (k & 1) ? -1.0f : 1.0f;
      if (k == 0 || k == M_NODES - 1) w *= 0.5f;
      if (d == 0.0f) {
        hit = k;
      } else {
        const float iv = w * RCP(d);
        num += (double)iv * (double)nd[k].y;
        den += (double)iv;
      }
    }
    const double F = (hit >= 0) ? (double)nd[hit].y : (num / den);
    dc += (double)yj / log2(F + 2.0);
  }
  for (int off = 32; off > 0; off >>= 1) dc += __shfl_down(dc, off);
  if (lane == 0) wsum[tid >> 6] = dc;
  __syncthreads();
  if (tid == 0) {
    double a = 0.0;
#pragma unroll
    for (int w = 0; w < 16; ++w) a += wsum[w];
    aaddd(&g_acc[0], a);
    WAIT_VM0();  // acc RMW complete at IF$ before the ticket
    const int old = afetchaddi(&g_done, 1);
    if (old == GBLKS - 1) {  // last block: all acc RMWs are at IF$
      const double dcg = aloadd(&g_acc[0]);
      const double idcg = aloadd(&g_acc[1]);
      const double yss = aloadd(&g_acc[2]);
      const double loss = 1.0 - dcg / (idcg + 1e-8);
      out[0] = (yss < 1.0) ? 0.0f : (float)loss;
      // self-clean for next graph replay (kernel boundary orders this)
      astored(&g_acc[0], 0.0);
      astored(&g_acc[1], 0.0);
      astored(&g_acc[2], 0.0);
      astorei(&g_done, 0);
      astorei(&g_bar, 0);
    }
  }
}

extern "C" void kernel_launch(void* const* d_in, const int* in_sizes, int n_in,
                              void* d_out, int out_size, void* d_ws,
                              size_t ws_size, hipStream_t stream) {
  const float* s = (const float*)d_in[0];
  const float* y = (const float*)d_in[1];
  const int n = in_sizes[0];
  (void)d_ws;
  (void)ws_size;  // ws poison is unconditional harness behavior — ws unused
  fused_kernel<<<GBLKS, BT, 0, stream>>>(s, y, (float*)d_out, n);
}

// Round 5
// 105.387 us; speedup vs baseline: 1.2166x; 1.2166x over previous
//
#include <hip/hip_runtime.h>

// ApproxNDCGLoss, N=20000, fp32 — TWO dispatches; kernel boundary as barrier.
//
// Round 2/3/4 post-mortem: every fused single-kernel variant (acquire-spin,
// fenced, relaxed-spin; work moved freely between phases) lands at 82-115 us
// with VALUBusy ~1.4% — duration invariant to work => the in-kernel grid
// barrier itself costs tens of us (64 blocks' uncached polls on one IF$ line
// starve the 65 serialized arrive-RMWs). Round 0's two plain kernels cost
// ~43 us combined. On this chip the dispatch boundary IS the cheap barrier.
//
// This version = round-0 skeleton + the barrier-orthogonal wins since:
//  - produce blk0: counting sort with ybkt+prefix in LDS (97 KB), 2-barrier
//    shuffle scan (was 30-barrier Hillis-Steele), and idcg+ysum computed
//    block-locally (round 0 paid ~10 uncoalesced global loads PER ELEMENT
//    for the rank scan in consume). Publishes two f64 atomicAdds.
//  - produce blk 1..64: Chebyshev node F_k sums (verified unchanged math);
//    plain float2 store to module global; boundary publishes.
//  - consume: dcg-only barycentric (1 elem/thread, 79x256), f64 reduce,
//    round-0-proven __threadfence + ticket finalize; self-cleaning resets
//    (module globals are never poisoned — no re-init dispatch needed).

#define LOG2E 1.442695040888963387f
#define M_NODES 64
#define XHALF 8.0
#define NB 2048
#define PI_D 3.14159265358979323846
#define BT 1024
#define LDS_N 20480
#define MAXN 131072

#if __has_builtin(__builtin_amdgcn_exp2f)
#define EXP2(x) __builtin_amdgcn_exp2f(x)
#else
#define EXP2(x) exp2f(x)
#endif

#if __has_builtin(__builtin_amdgcn_rcpf)
#define RCP(x) __builtin_amdgcn_rcpf(x)
#else
#define RCP(x) (1.0f / (x))
#endif

// ---- module-global state (poison-free; visibility via kernel boundary) ----
__device__ double g_acc[3] = {0.0, 0.0, 0.0};  // dcg, idcg, ysum
__device__ int g_done = 0;
__device__ float2 g_nodes[M_NODES];  // (x_k, F_k)
__device__ float g_ybkt[MAXN];       // produce-blk0-private fallback (n>LDS_N)

__device__ __forceinline__ int bucket_of(float y) {
  int b = (int)(y * (float)NB);
  return b < 0 ? 0 : (b > NB - 1 ? NB - 1 : b);
}

// ---- produce: blk 0 = sort + idcg + ysum (LDS-local); blk 1..64 = nodes ----
__global__ __launch_bounds__(BT) void produce_kernel(
    const float* __restrict__ s, const float* __restrict__ y, int n) {
  const int tid = threadIdx.x;
  const int blk = blockIdx.x;
  const int lane = tid & 63;

  __shared__ int hist[NB];           // histogram, then scatter cursor
  __shared__ int sprefix[NB + 1];    // bucket starts
  __shared__ float ybkt_lds[LDS_N];  // sorted y
  __shared__ double wsum[32];        // reduction scratch
  __shared__ int wrep[16];           // scan wave partials

  if (blk == 0) {
    // --- counting sort of y ---
    for (int b = tid; b < NB; b += BT) hist[b] = 0;
    __syncthreads();

    const float4* y4 = (const float4*)y;
    const int n4 = n >> 2;
    for (int i = tid; i < n4; i += BT) {
      const float4 v = y4[i];
      atomicAdd(&hist[bucket_of(v.x)], 1);
      atomicAdd(&hist[bucket_of(v.y)], 1);
      atomicAdd(&hist[bucket_of(v.z)], 1);
      atomicAdd(&hist[bucket_of(v.w)], 1);
    }
    for (int i = (n4 << 2) + tid; i < n; i += BT)
      atomicAdd(&hist[bucket_of(y[i])], 1);
    __syncthreads();

    // exclusive scan (2 bins/thread), shuffle-based, 2 barriers
    const int base = tid * 2;
    const int l0 = hist[base], l1 = hist[base + 1];
    const int sum2 = l0 + l1;
    int v = sum2;
#pragma unroll
    for (int d = 1; d < 64; d <<= 1) {
      const int t = __shfl_up(v, d);
      if (lane >= d) v += t;
    }
    if (lane == 63) wrep[tid >> 6] = v;
    __syncthreads();
    if (tid < 16) {
      int wv = wrep[tid];
#pragma unroll
      for (int d = 1; d < 16; d <<= 1) {
        const int t = __shfl_up(wv, d);
        if (tid >= d) wv += t;
      }
      wrep[tid] = wv;
    }
    __syncthreads();
    const int wbase = (tid >> 6) ? wrep[(tid >> 6) - 1] : 0;
    const int incl = wbase + v;
    const int run = incl - sum2;
    sprefix[base] = run;
    sprefix[base + 1] = run + l0;
    if (tid == BT - 1) sprefix[NB] = incl;  // == n
    hist[base] = run;  // scatter cursor
    hist[base + 1] = run + l0;
    __syncthreads();

    // scatter + rank-count, parameterized on ybkt storage (LDS fast path)
    double ic = 0.0, ys = 0.0;
    auto sort_body = [&](float* ybkt) {
      for (int i = tid; i < n4; i += BT) {
        const float4 v4 = y4[i];
        ybkt[atomicAdd(&hist[bucket_of(v4.x)], 1)] = v4.x;
        ybkt[atomicAdd(&hist[bucket_of(v4.y)], 1)] = v4.y;
        ybkt[atomicAdd(&hist[bucket_of(v4.z)], 1)] = v4.z;
        ybkt[atomicAdd(&hist[bucket_of(v4.w)], 1)] = v4.w;
      }
      for (int i = (n4 << 2) + tid; i < n; i += BT) {
        const float yv = y[i];
        ybkt[atomicAdd(&hist[bucket_of(yv)], 1)] = yv;
      }
      __syncthreads();  // scatter complete before same-block reads

      // idcg + ysum: exact rank = 1 + #(strictly greater), LDS-local
      for (int i = tid; i < n; i += BT) {
        const float yv = y[i];
        const int b = bucket_of(yv);
        const int s0 = sprefix[b], s1 = sprefix[b + 1];
        int cnt = n - s1;  // strictly higher buckets
        for (int t = s0; t < s1; ++t) cnt += (ybkt[t] > yv);
        ic += (double)yv / log2((double)cnt + 2.0);
        ys += (double)yv;
      }
    };
    if (n <= LDS_N) sort_body(ybkt_lds);
    else sort_body(g_ybkt);  // block-private global fallback

    for (int off = 32; off > 0; off >>= 1) {
      ic += __shfl_down(ic, off);
      ys += __shfl_down(ys, off);
    }
    if (lane == 0) {
      wsum[tid >> 6] = ic;
      wsum[(tid >> 6) + 16] = ys;
    }
    __syncthreads();
    if (tid == 0) {
      double b = 0.0, c = 0.0;
#pragma unroll
      for (int w = 0; w < 16; ++w) {
        b += wsum[w];
        c += wsum[w + 16];
      }
      atomicAdd(&g_acc[1], b);  // visible to consume via kernel boundary
      atomicAdd(&g_acc[2], c);
    }
  } else {
    // --- node k: F(x_k) = sum_i sigmoid(x_k - s_i) ---
    const int k = blk - 1;
    const float xk =
        (float)(XHALF * cos(PI_D * (double)k / (double)(M_NODES - 1)));
    double F = 0.0;
    const float4* s4 = (const float4*)s;
    const int n4 = n >> 2;
    for (int i = tid; i < n4; i += BT) {
      const float4 v = s4[i];
      float t = RCP(1.0f + EXP2((v.x - xk) * LOG2E));
      t += RCP(1.0f + EXP2((v.y - xk) * LOG2E));
      t += RCP(1.0f + EXP2((v.z - xk) * LOG2E));
      t += RCP(1.0f + EXP2((v.w - xk) * LOG2E));
      F += (double)t;
    }
    for (int i = (n4 << 2) + tid; i < n; i += BT)
      F += (double)RCP(1.0f + EXP2((s[i] - xk) * LOG2E));
    for (int off = 32; off > 0; off >>= 1) F += __shfl_down(F, off);
    if (lane == 0) wsum[tid >> 6] = F;
    __syncthreads();
    if (tid == 0) {
      double t = 0.0;
#pragma unroll
      for (int w = 0; w < 16; ++w) t += wsum[w];
      g_nodes[k] = make_float2(xk, (float)t);  // plain store; boundary pubs
    }
  }
}

// ---- consume: dcg-only barycentric + reduce + ticket finalize ----
__global__ __launch_bounds__(256) void consume_kernel(
    const float* __restrict__ s, const float* __restrict__ y,
    float* __restrict__ out, int n, int nblocks) {
  __shared__ float2 nd[M_NODES];
  __shared__ double wsum[4];
  const int tid = threadIdx.x;
  if (tid < M_NODES) nd[tid] = g_nodes[tid];
  __syncthreads();

  const int j = blockIdx.x * 256 + tid;
  double dc = 0.0;
  if (j < n) {
    const float x = s[j];
    const float yj = y[j];
    double num = 0.0, den = 0.0;
    int hit = -1;
#pragma unroll
    for (int k = 0; k < M_NODES; ++k) {
      const float d = x - nd[k].x;
      float w = (k & 1) ? -1.0f : 1.0f;
      if (k == 0 || k == M_NODES - 1) w *= 0.5f;
      if (d == 0.0f) {
        hit = k;
      } else {
        const float iv = w * RCP(d);
        num += (double)iv * (double)nd[k].y;
        den += (double)iv;
      }
    }
    const double F = (hit >= 0) ? (double)nd[hit].y : (num / den);
    dc = (double)yj / log2(F + 2.0);
  }
  for (int off = 32; off > 0; off >>= 1) dc += __shfl_down(dc, off);
  if ((tid & 63) == 0) wsum[tid >> 6] = dc;
  __syncthreads();
  if (tid == 0) {
    atomicAdd(&g_acc[0], wsum[0] + wsum[1] + wsum[2] + wsum[3]);
    __threadfence();
    const int old = atomicAdd(&g_done, 1);
    if (old == nblocks - 1) {  // last block: all acc updates visible
      const double dcg = atomicAdd(&g_acc[0], 0.0);
      const double idcg = atomicAdd(&g_acc[1], 0.0);
      const double ysum = atomicAdd(&g_acc[2], 0.0);
      const double loss = 1.0 - dcg / (idcg + 1e-8);
      out[0] = (ysum < 1.0) ? 0.0f : (float)loss;
      // self-clean for next replay (visible via kernel boundary)
      g_acc[0] = 0.0;
      g_acc[1] = 0.0;
      g_acc[2] = 0.0;
      g_done = 0;
      __threadfence();
    }
  }
}

extern "C" void kernel_launch(void* const* d_in, const int* in_sizes, int n_in,
                              void* d_out, int out_size, void* d_ws,
                              size_t ws_size, hipStream_t stream) {
  const float* s = (const float*)d_in[0];
  const float* y = (const float*)d_in[1];
  const int n = in_sizes[0];
  (void)d_ws;
  (void)ws_size;  // ws poison is unconditional; module globals are poison-free

  const int nb = (n + 255) / 256;
  produce_kernel<<<M_NODES + 1, BT, 0, stream>>>(s, y, n);
  consume_kernel<<<nb, 256, 0, stream>>>(s, y, (float*)d_out, n, nb);
}

// Round 6
// 80.761 us; speedup vs baseline: 1.5875x; 1.3049x over previous
//
#include <hip/hip_runtime.h>

// ApproxNDCGLoss, N=20000, fp32 — TWO dispatches, round-0 work split restored.
//
// Round-5 post-mortem: produce=44 us (top dispatch, above the 39.5 us fills).
// Its straggler is block 0: I had moved the idcg rank-scan + per-element f64
// log2/div onto the single-CU sort block (1 block/CU at 99 KB LDS, 16 waves,
// divergent inner loop) — tens of us serial while 191 CUs idle. Also risky:
// sort_body(float*) generic-pointer lambda (LDS + global call sites) may have
// compiled LDS traffic to flat ops. Round-0's split (sort-only block 0;
// rank-scan in 20000-thread consume from L2-resident global) measured ~43 us
// combined — restore it, keep the barrier-orthogonal wins:
//   - 2-barrier shuffle scan (round-5-verified) instead of 30-barrier
//     Hillis-Steele in block 0
//   - direct LDS arrays, no generic pointers anywhere
//   - module __device__ globals (no ws, no re-init dispatch), proven
//     ticket finalize + self-clean
// Known-immovable floor: harness 256 MiB ws-poison fill at 39.5 us/iter.

#define LOG2E 1.442695040888963387f
#define M_NODES 64
#define XHALF 8.0
#define NB 2048
#define PI_D 3.14159265358979323846
#define BT 1024
#define MAXN 131072

#if __has_builtin(__builtin_amdgcn_exp2f)
#define EXP2(x) __builtin_amdgcn_exp2f(x)
#else
#define EXP2(x) exp2f(x)
#endif

#if __has_builtin(__builtin_amdgcn_rcpf)
#define RCP(x) __builtin_amdgcn_rcpf(x)
#else
#define RCP(x) (1.0f / (x))
#endif

// ---- module-global state (poison-free; visibility via kernel boundary) ----
__device__ double g_acc[3] = {0.0, 0.0, 0.0};  // dcg, idcg, ysum
__device__ int g_done = 0;
__device__ float2 g_nodes[M_NODES];  // (x_k, F_k)
__device__ int g_prefix[NB + 1];     // bucket starts
__device__ float g_ybkt[MAXN];       // bucket-sorted y

__device__ __forceinline__ int bucket_of(float y) {
  int b = (int)(y * (float)NB);
  return b < 0 ? 0 : (b > NB - 1 ? NB - 1 : b);
}

// ---- produce: blk 0 = counting sort ONLY; blk 1..64 = Chebyshev nodes ----
__global__ __launch_bounds__(BT) void produce_kernel(
    const float* __restrict__ s, const float* __restrict__ y, int n) {
  const int tid = threadIdx.x;
  const int blk = blockIdx.x;
  const int lane = tid & 63;

  __shared__ int hist[NB];     // histogram, then scatter cursor (8 KB)
  __shared__ int wrep[16];     // scan wave partials
  __shared__ double wsum[16];  // node reduction scratch

  if (blk == 0) {
    // --- histogram ---
    for (int b = tid; b < NB; b += BT) hist[b] = 0;
    __syncthreads();

    const float4* y4 = (const float4*)y;
    const int n4 = n >> 2;
    for (int i = tid; i < n4; i += BT) {
      const float4 v = y4[i];
      atomicAdd(&hist[bucket_of(v.x)], 1);
      atomicAdd(&hist[bucket_of(v.y)], 1);
      atomicAdd(&hist[bucket_of(v.z)], 1);
      atomicAdd(&hist[bucket_of(v.w)], 1);
    }
    for (int i = (n4 << 2) + tid; i < n; i += BT)
      atomicAdd(&hist[bucket_of(y[i])], 1);
    __syncthreads();

    // --- exclusive scan (2 bins/thread), shuffle-based, 2 barriers ---
    const int base = tid * 2;
    const int l0 = hist[base], l1 = hist[base + 1];
    const int sum2 = l0 + l1;
    int v = sum2;
#pragma unroll
    for (int d = 1; d < 64; d <<= 1) {
      const int t = __shfl_up(v, d);
      if (lane >= d) v += t;
    }
    if (lane == 63) wrep[tid >> 6] = v;
    __syncthreads();
    if (tid < 16) {
      int wv = wrep[tid];
#pragma unroll
      for (int d = 1; d < 16; d <<= 1) {
        const int t = __shfl_up(wv, d);
        if (tid >= d) wv += t;
      }
      wrep[tid] = wv;
    }
    __syncthreads();
    const int wbase = (tid >> 6) ? wrep[(tid >> 6) - 1] : 0;
    const int incl = wbase + v;
    const int run = incl - sum2;  // exclusive prefix of this 2-bin chunk
    g_prefix[base] = run;         // publish (boundary makes it visible)
    g_prefix[base + 1] = run + l0;
    if (tid == BT - 1) g_prefix[NB] = incl;  // == n
    hist[base] = run;  // LDS scatter cursor
    hist[base + 1] = run + l0;
    __syncthreads();

    // --- scatter to global (plain stores; consume reads after boundary) ---
    for (int i = tid; i < n4; i += BT) {
      const float4 v4 = y4[i];
      g_ybkt[atomicAdd(&hist[bucket_of(v4.x)], 1)] = v4.x;
      g_ybkt[atomicAdd(&hist[bucket_of(v4.y)], 1)] = v4.y;
      g_ybkt[atomicAdd(&hist[bucket_of(v4.z)], 1)] = v4.z;
      g_ybkt[atomicAdd(&hist[bucket_of(v4.w)], 1)] = v4.w;
    }
    for (int i = (n4 << 2) + tid; i < n; i += BT) {
      const float yv = y[i];
      g_ybkt[atomicAdd(&hist[bucket_of(yv)], 1)] = yv;
    }
  } else {
    // --- node k: F(x_k) = sum_i sigmoid(x_k - s_i) (verified math) ---
    const int k = blk - 1;
    const float xk =
        (float)(XHALF * cos(PI_D * (double)k / (double)(M_NODES - 1)));
    double F = 0.0;
    const float4* s4 = (const float4*)s;
    const int n4 = n >> 2;
    for (int i = tid; i < n4; i += BT) {
      const float4 v = s4[i];
      float t = RCP(1.0f + EXP2((v.x - xk) * LOG2E));
      t += RCP(1.0f + EXP2((v.y - xk) * LOG2E));
      t += RCP(1.0f + EXP2((v.z - xk) * LOG2E));
      t += RCP(1.0f + EXP2((v.w - xk) * LOG2E));
      F += (double)t;
    }
    for (int i = (n4 << 2) + tid; i < n; i += BT)
      F += (double)RCP(1.0f + EXP2((s[i] - xk) * LOG2E));
    for (int off = 32; off > 0; off >>= 1) F += __shfl_down(F, off);
    if (lane == 0) wsum[tid >> 6] = F;
    __syncthreads();
    if (tid == 0) {
      double t = 0.0;
#pragma unroll
      for (int w = 0; w < 16; ++w) t += wsum[w];
      g_nodes[k] = make_float2(xk, (float)t);
    }
  }
}

// ---- consume: barycentric dcg + parallel rank-scan idcg + finalize ----
__global__ __launch_bounds__(256) void consume_kernel(
    const float* __restrict__ s, const float* __restrict__ y,
    float* __restrict__ out, int n, int nblocks) {
  __shared__ float2 nd[M_NODES];
  __shared__ double wsum[12];
  const int tid = threadIdx.x;
  if (tid < M_NODES) nd[tid] = g_nodes[tid];
  __syncthreads();

  const int j = blockIdx.x * 256 + tid;
  double dc = 0.0, ic = 0.0, ys = 0.0;
  if (j < n) {
    const float x = s[j];
    const float yj = y[j];
    // dcg: barycentric interpolation of F(s_j) over 64 Chebyshev nodes
    double num = 0.0, den = 0.0;
    int hit = -1;
#pragma unroll
    for (int k = 0; k < M_NODES; ++k) {
      const float d = x - nd[k].x;
      float w = (k & 1) ? -1.0f : 1.0f;
      if (k == 0 || k == M_NODES - 1) w *= 0.5f;
      if (d == 0.0f) {
        hit = k;
      } else {
        const float iv = w * RCP(d);
        num += (double)iv * (double)nd[k].y;
        den += (double)iv;
      }
    }
    const double F = (hit >= 0) ? (double)nd[hit].y : (num / den);

    // idcg: exact rank = 1 + #(strictly greater); L2-resident bucket scan
    const int b = bucket_of(yj);
    const int s0 = g_prefix[b];
    const int s1 = g_prefix[b + 1];
    int cnt = n - s1;  // strictly higher buckets
    for (int t = s0; t < s1; ++t) cnt += (g_ybkt[t] > yj);

    dc = (double)yj / log2(F + 2.0);
    ic = (double)yj / log2((double)cnt + 2.0);
    ys = (double)yj;
  }
  for (int off = 32; off > 0; off >>= 1) {
    dc += __shfl_down(dc, off);
    ic += __shfl_down(ic, off);
    ys += __shfl_down(ys, off);
  }
  const int wv = tid >> 6;
  if ((tid & 63) == 0) {
    wsum[wv] = dc;
    wsum[wv + 4] = ic;
    wsum[wv + 8] = ys;
  }
  __syncthreads();
  if (tid == 0) {
    atomicAdd(&g_acc[0], wsum[0] + wsum[1] + wsum[2] + wsum[3]);
    atomicAdd(&g_acc[1], wsum[4] + wsum[5] + wsum[6] + wsum[7]);
    atomicAdd(&g_acc[2], wsum[8] + wsum[9] + wsum[10] + wsum[11]);
    __threadfence();
    const int old = atomicAdd(&g_done, 1);
    if (old == nblocks - 1) {  // last block: all acc updates visible
      const double dcg = atomicAdd(&g_acc[0], 0.0);
      const double idcg = atomicAdd(&g_acc[1], 0.0);
      const double ysum = atomicAdd(&g_acc[2], 0.0);
      const double loss = 1.0 - dcg / (idcg + 1e-8);
      out[0] = (ysum < 1.0) ? 0.0f : (float)loss;
      // self-clean for next replay (visible via kernel boundary)
      g_acc[0] = 0.0;
      g_acc[1] = 0.0;
      g_acc[2] = 0.0;
      g_done = 0;
      __threadfence();
    }
  }
}

extern "C" void kernel_launch(void* const* d_in, const int* in_sizes, int n_in,
                              void* d_out, int out_size, void* d_ws,
                              size_t ws_size, hipStream_t stream) {
  const float* s = (const float*)d_in[0];
  const float* y = (const float*)d_in[1];
  const int n = in_sizes[0];
  (void)d_ws;
  (void)ws_size;  // ws poison is unconditional; module globals are poison-free

  const int nb = (n + 255) / 256;
  produce_kernel<<<M_NODES + 1, BT, 0, stream>>>(s, y, n);
  consume_kernel<<<nb, 256, 0, stream>>>(s, y, (float*)d_out, n, nb);
}